// Round 4
// baseline (609.941 us; speedup 1.0000x reference)
//
#include <hip/hip_runtime.h>
#include <hip/hip_bf16.h>
#include <stdint.h>

#define N_NODES 100000
#define N_EDGES 3200000
#define D_FEAT 256
#define NBKT 782      // ceil(N_NODES / 128) buckets (row >> 7)
#define RPB 128       // rows per bucket
#define CHUNK 8192    // edges per coarse block
#define NBLK_E 391    // ceil(N_EDGES / CHUNK)
#define CAP 6144      // LDS edge capacity per bucket (mean 4096, sigma ~64 -> 32 sigma)

typedef __attribute__((ext_vector_type(8))) short short8;
typedef __attribute__((ext_vector_type(8))) ushort ushort8;
typedef __attribute__((ext_vector_type(4))) float float4v;

__device__ inline unsigned short f2bf(float f) {
    union { float f; unsigned u; } v; v.f = f;
    unsigned u = v.u;
    u += 0x7FFF + ((u >> 16) & 1);   // round-to-nearest-even
    return (unsigned short)(u >> 16);
}
__device__ inline float bf2f(unsigned short u) {
    union { unsigned u; float f; } v; v.u = (unsigned)u << 16;
    return v.f;
}

// ---- x fp32 -> bf16 (streaming) -----------------------------------------
__global__ __launch_bounds__(256) void xconv_kernel(const float4* __restrict__ x4,
                                                    ushort4* __restrict__ xbf4) {
    int i = blockIdx.x * 256 + threadIdx.x;   // 25000 blocks, exact
    float4 v = x4[i];
    ushort4 o;
    o.x = f2bf(v.x); o.y = f2bf(v.y); o.z = f2bf(v.z); o.w = f2bf(v.w);
    xbf4[i] = o;
}

// ---- CSR-ish build: coarse bucket sort (row >> 7) -----------------------

__global__ __launch_bounds__(256) void coarse_hist(const int* __restrict__ erow,
                                                   int* __restrict__ hist) {
    __shared__ int cnt[NBKT];
    for (int b = threadIdx.x; b < NBKT; b += 256) cnt[b] = 0;
    __syncthreads();
    int cb = blockIdx.x * CHUNK;
    for (int j = 0; j < CHUNK; j += 256) {
        int i = cb + j + threadIdx.x;
        if (i < N_EDGES) atomicAdd(&cnt[erow[i] >> 7], 1);
    }
    __syncthreads();
    for (int b = threadIdx.x; b < NBKT; b += 256)
        hist[blockIdx.x * NBKT + b] = cnt[b];
}

// per-bucket exclusive scan over chunk-blocks (in-place), emit totals
__global__ __launch_bounds__(512) void scan_blocks(int* __restrict__ hist,
                                                   int* __restrict__ totals) {
    __shared__ int s[512];
    int b = blockIdx.x;          // bucket
    int t = threadIdx.x;
    int v = (t < NBLK_E) ? hist[t * NBKT + b] : 0;
    s[t] = v;
    __syncthreads();
    for (int o = 1; o < 512; o <<= 1) {
        int x = (t >= o) ? s[t - o] : 0;
        __syncthreads();
        s[t] += x;
        __syncthreads();
    }
    if (t < NBLK_E) hist[t * NBKT + b] = s[t] - v;   // exclusive within bucket
    if (t == NBLK_E - 1) totals[b] = s[t];
}

// exclusive scan of bucket totals -> bucket bases
__global__ __launch_bounds__(1024) void scan_buckets(const int* __restrict__ totals,
                                                     int* __restrict__ base_) {
    __shared__ int s[1024];
    int t = threadIdx.x;
    int v = (t < NBKT) ? totals[t] : 0;
    s[t] = v;
    __syncthreads();
    for (int o = 1; o < 1024; o <<= 1) {
        int x = (t >= o) ? s[t - o] : 0;
        __syncthreads();
        s[t] += x;
        __syncthreads();
    }
    if (t < NBKT) base_[t] = s[t] - v;
    if (t == 0) base_[NBKT] = N_EDGES;
}

// coarse scatter into bucket-ordered tmp (LDS cursors, semi-coalesced writes)
__global__ __launch_bounds__(256) void coarse_scatter(
        const int* __restrict__ erow, const int* __restrict__ ecol,
        const float* __restrict__ eval,
        const int* __restrict__ hist, const int* __restrict__ base_,
        uint2* __restrict__ tmp) {
    __shared__ int lbase[NBKT];
    __shared__ int cnt[NBKT];
    for (int b = threadIdx.x; b < NBKT; b += 256) {
        lbase[b] = hist[blockIdx.x * NBKT + b] + base_[b];
        cnt[b] = 0;
    }
    __syncthreads();
    int cb = blockIdx.x * CHUNK;
    for (int j = 0; j < CHUNK; j += 256) {
        int i = cb + j + threadIdx.x;
        if (i < N_EDGES) {
            int r = erow[i];
            int b = r >> 7;
            int pos = lbase[b] + atomicAdd(&cnt[b], 1);
            uint2 cv;
            cv.x = (unsigned)ecol[i] | ((unsigned)(r & 127) << 17);  // col < 2^17
            union { float f; unsigned u; } w; w.f = eval[i];
            cv.y = w.u;
            tmp[pos] = cv;
        }
    }
}

// ---- Fused fine-sort + SpMM: one block per bucket -----------------------
// Phase 1: LDS counting sort of the bucket's edges by row-low-7.
// Phase 2: per-row register aggregation, half-wave per edge, 4 in flight.
__global__ __launch_bounds__(512) void spmm_fused(
        const ushort* __restrict__ xbf,      // [N][256] bf16
        const uint2* __restrict__ tmp,       // bucket-ordered edges
        const int* __restrict__ base_,
        ushort* __restrict__ agg_bf) {       // [N][256] bf16
    __shared__ uint2 ed[CAP];
    __shared__ int cnt[RPB];
    __shared__ int excl[RPB];
    __shared__ int cur[RPB];
    int b = blockIdx.x;
    int t = threadIdx.x;
    int s0 = base_[b];
    int nb = base_[b + 1] - s0;

    if (t < RPB) cnt[t] = 0;
    __syncthreads();
    for (int j = t; j < nb; j += 512)
        atomicAdd(&cnt[(tmp[s0 + j].x >> 17) & 127], 1);
    __syncthreads();
    // inclusive scan of cnt into excl (block-wide Hillis-Steele on 128)
    if (t < RPB) excl[t] = cnt[t];
    __syncthreads();
    for (int o = 1; o < RPB; o <<= 1) {
        int x = (t < RPB && t >= o) ? excl[t - o] : 0;
        __syncthreads();
        if (t < RPB) excl[t] += x;
        __syncthreads();
    }
    if (t < RPB) { int ex = excl[t] - cnt[t]; excl[t] = ex; cur[t] = ex; }
    __syncthreads();
    for (int j = t; j < nb; j += 512) {
        uint2 cv = tmp[s0 + j];
        unsigned rl = (cv.x >> 17) & 127;
        int dst = atomicAdd(&cur[rl], 1);
        ed[dst] = cv;
    }
    __syncthreads();

    // aggregation: 8 waves, each handles rows wv, wv+8, ...
    int wv   = t >> 6;
    int lane = t & 63;
    int half = lane >> 5;
    int hl   = lane & 31;
    for (int rl = wv; rl < RPB; rl += 8) {
        int row = b * RPB + rl;
        if (row >= N_NODES) break;
        int sE = excl[rl];
        int eE = sE + cnt[rl];
        float acc[8] = {0.f, 0.f, 0.f, 0.f, 0.f, 0.f, 0.f, 0.f};
        int e = sE + half;
        for (; e + 6 < eE; e += 8) {      // 4 edges in flight per half-wave
            uint2 c0 = ed[e];
            uint2 c1 = ed[e + 2];
            uint2 c2 = ed[e + 4];
            uint2 c3 = ed[e + 6];
            ushort8 v0 = *(const ushort8*)&xbf[(size_t)(c0.x & 0x1FFFF) * 256 + hl * 8];
            ushort8 v1 = *(const ushort8*)&xbf[(size_t)(c1.x & 0x1FFFF) * 256 + hl * 8];
            ushort8 v2 = *(const ushort8*)&xbf[(size_t)(c2.x & 0x1FFFF) * 256 + hl * 8];
            ushort8 v3 = *(const ushort8*)&xbf[(size_t)(c3.x & 0x1FFFF) * 256 + hl * 8];
            union { unsigned u; float f; } w0, w1, w2, w3;
            w0.u = c0.y; w1.u = c1.y; w2.u = c2.y; w3.u = c3.y;
            #pragma unroll
            for (int j = 0; j < 8; ++j) acc[j] += w0.f * bf2f(v0[j]);
            #pragma unroll
            for (int j = 0; j < 8; ++j) acc[j] += w1.f * bf2f(v1[j]);
            #pragma unroll
            for (int j = 0; j < 8; ++j) acc[j] += w2.f * bf2f(v2[j]);
            #pragma unroll
            for (int j = 0; j < 8; ++j) acc[j] += w3.f * bf2f(v3[j]);
        }
        for (; e < eE; e += 2) {
            uint2 cv = ed[e];
            ushort8 v = *(const ushort8*)&xbf[(size_t)(cv.x & 0x1FFFF) * 256 + hl * 8];
            union { unsigned u; float f; } w; w.u = cv.y;
            #pragma unroll
            for (int j = 0; j < 8; ++j) acc[j] += w.f * bf2f(v[j]);
        }
        #pragma unroll
        for (int j = 0; j < 8; ++j) acc[j] += __shfl_xor(acc[j], 32, 64);
        if (half == 0) {
            ushort8 o;
            #pragma unroll
            for (int j = 0; j < 8; ++j) o[j] = f2bf(acc[j]);
            *(ushort8*)&agg_bf[(size_t)row * 256 + hl * 8] = o;
        }
    }
}

// ---- W fp32 -> bf16 ------------------------------------------------------
__global__ void wconv_kernel(const float* __restrict__ W, ushort* __restrict__ Wbf) {
    int i = blockIdx.x * 256 + threadIdx.x;
    Wbf[i] = f2bf(W[i]);
}

// ---- GEMM: 64 rows/block, 4x W reuse per wave ---------------------------
__global__ __launch_bounds__(256) void gemm_kernel(
        const ushort* __restrict__ Abf,   // [N][256] bf16
        const ushort* __restrict__ Wbf,   // [256][256] bf16, n-major
        float* __restrict__ out) {        // [N][256] fp32
    int w    = threadIdx.x >> 6;
    int lane = threadIdx.x & 63;
    int quad = lane >> 4;
    int l16  = lane & 15;
    int rt   = blockIdx.x * 64;           // 1563 blocks

    float4v acc[4][4];
    #pragma unroll
    for (int mt = 0; mt < 4; ++mt)
        #pragma unroll
        for (int nt = 0; nt < 4; ++nt) acc[mt][nt] = (float4v){0.f, 0.f, 0.f, 0.f};

    #pragma unroll
    for (int k0 = 0; k0 < 256; k0 += 32) {
        short8 a[4], bf[4];
        #pragma unroll
        for (int mt = 0; mt < 4; ++mt) {
            int row = rt + mt * 16 + l16;
            if (row >= N_NODES) row = N_NODES - 1;   // clamp (tail block)
            a[mt] = *(const short8*)&Abf[(size_t)row * 256 + k0 + quad * 8];
        }
        #pragma unroll
        for (int nt = 0; nt < 4; ++nt) {
            int n = w * 64 + nt * 16 + l16;
            bf[nt] = *(const short8*)&Wbf[n * 256 + k0 + quad * 8];
        }
        #pragma unroll
        for (int mt = 0; mt < 4; ++mt)
            #pragma unroll
            for (int nt = 0; nt < 4; ++nt)
                acc[mt][nt] = __builtin_amdgcn_mfma_f32_16x16x32_bf16(a[mt], bf[nt], acc[mt][nt], 0, 0, 0);
    }
    #pragma unroll
    for (int mt = 0; mt < 4; ++mt)
        #pragma unroll
        for (int nt = 0; nt < 4; ++nt) {
            int n = w * 64 + nt * 16 + l16;
            #pragma unroll
            for (int r = 0; r < 4; ++r) {
                int row = rt + mt * 16 + quad * 4 + r;   // C/D: col=lane&15, row=quad*4+reg
                if (row < N_NODES) out[(size_t)row * 256 + n] = acc[mt][nt][r];
            }
        }
}

// ---- launch --------------------------------------------------------------

extern "C" void kernel_launch(void* const* d_in, const int* in_sizes, int n_in,
                              void* d_out, int out_size, void* d_ws, size_t ws_size,
                              hipStream_t stream) {
    const float* x    = (const float*)d_in[0];
    const int*   erow = (const int*)d_in[1];
    const int*   ecol = (const int*)d_in[2];
    const float* eval = (const float*)d_in[3];
    const float* W    = (const float*)d_in[4];
    float* out = (float*)d_out;

    char* ws = (char*)d_ws;
    size_t off = 0;
    int* hist      = (int*)(ws + off);   off += ((size_t)NBLK_E * NBKT * 4 + 255) & ~255ull;
    int* totals    = (int*)(ws + off);   off += ((size_t)NBKT * 4 + 255) & ~255ull;
    int* base_     = (int*)(ws + off);   off += ((size_t)(NBKT + 1) * 4 + 255) & ~255ull;
    uint2* tmp_cv  = (uint2*)(ws + off); off += (size_t)N_EDGES * 8;
    ushort* Wbf    = (ushort*)(ws + off);  off += (size_t)D_FEAT * D_FEAT * 2;
    ushort* xbf    = (ushort*)(ws + off);  off += (size_t)N_NODES * D_FEAT * 2;
    ushort* agg_bf = (ushort*)(ws + off);  off += (size_t)N_NODES * D_FEAT * 2;

    xconv_kernel<<<(N_NODES * D_FEAT / 4) / 256, 256, 0, stream>>>((const float4*)x, (ushort4*)xbf);
    coarse_hist<<<NBLK_E, 256, 0, stream>>>(erow, hist);
    scan_blocks<<<NBKT, 512, 0, stream>>>(hist, totals);
    scan_buckets<<<1, 1024, 0, stream>>>(totals, base_);
    coarse_scatter<<<NBLK_E, 256, 0, stream>>>(erow, ecol, eval, hist, base_, tmp_cv);
    wconv_kernel<<<(D_FEAT * D_FEAT) / 256, 256, 0, stream>>>(W, Wbf);
    spmm_fused<<<NBKT, 512, 0, stream>>>(xbf, tmp_cv, base_, agg_bf);
    gemm_kernel<<<(N_NODES + 63) / 64, 256, 0, stream>>>(agg_bf, Wbf, out);
}

// Round 5
// 598.576 us; speedup vs baseline: 1.0190x; 1.0190x over previous
//
#include <hip/hip_runtime.h>
#include <hip/hip_bf16.h>
#include <stdint.h>

#define N_NODES 100000
#define N_EDGES 3200000
#define D_FEAT 256
#define NBKT 782      // ceil(N_NODES / 128) buckets (row >> 7)
#define RPB 128       // rows per bucket
#define CHUNK 2048    // edges per coarse block
#define NBLK_E 1563   // ceil(N_EDGES / CHUNK)

typedef __attribute__((ext_vector_type(8))) short short8;
typedef __attribute__((ext_vector_type(8))) ushort ushort8;
typedef __attribute__((ext_vector_type(4))) float float4v;

__device__ inline unsigned short f2bf(float f) {
    union { float f; unsigned u; } v; v.f = f;
    unsigned u = v.u;
    u += 0x7FFF + ((u >> 16) & 1);   // round-to-nearest-even
    return (unsigned short)(u >> 16);
}
__device__ inline float bf2f(unsigned short u) {
    union { unsigned u; float f; } v; v.u = (unsigned)u << 16;
    return v.f;
}

// ---- x fp32 -> bf16 (streaming) -----------------------------------------
__global__ __launch_bounds__(256) void xconv_kernel(const float4* __restrict__ x4,
                                                    ushort4* __restrict__ xbf4) {
    int i = blockIdx.x * 256 + threadIdx.x;   // 25000 blocks, exact
    float4 v = x4[i];
    ushort4 o;
    o.x = f2bf(v.x); o.y = f2bf(v.y); o.z = f2bf(v.z); o.w = f2bf(v.w);
    xbf4[i] = o;
}

// ---- bucket build (row >> 7), CHUNK=2048 for occupancy ------------------

__global__ __launch_bounds__(256) void coarse_hist(const int* __restrict__ erow,
                                                   int* __restrict__ hist) {
    __shared__ int cnt[NBKT];
    for (int b = threadIdx.x; b < NBKT; b += 256) cnt[b] = 0;
    __syncthreads();
    int cb = blockIdx.x * CHUNK;
    #pragma unroll
    for (int j = 0; j < CHUNK; j += 256) {
        int i = cb + j + threadIdx.x;
        if (i < N_EDGES) atomicAdd(&cnt[erow[i] >> 7], 1);
    }
    __syncthreads();
    for (int b = threadIdx.x; b < NBKT; b += 256)
        hist[blockIdx.x * NBKT + b] = cnt[b];
}

// per-bucket exclusive scan over 1563 chunk-blocks: 4 serial per thread +
// Hillis-Steele over 512. One block per bucket.
__global__ __launch_bounds__(512) void scan_blocks(int* __restrict__ hist,
                                                   int* __restrict__ totals) {
    __shared__ int s[512];
    int b = blockIdx.x;
    int t = threadIdx.x;
    int v[4];
    int sum = 0;
    #pragma unroll
    for (int j = 0; j < 4; ++j) {
        int c = t * 4 + j;
        v[j] = (c < NBLK_E) ? hist[c * NBKT + b] : 0;
        sum += v[j];
    }
    s[t] = sum;
    __syncthreads();
    for (int o = 1; o < 512; o <<= 1) {
        int x = (t >= o) ? s[t - o] : 0;
        __syncthreads();
        s[t] += x;
        __syncthreads();
    }
    int run = s[t] - sum;   // exclusive base for this thread's 4 chunks
    #pragma unroll
    for (int j = 0; j < 4; ++j) {
        int c = t * 4 + j;
        if (c < NBLK_E) { hist[c * NBKT + b] = run; run += v[j]; }
    }
    if (t == 511) totals[b] = run;
}

// exclusive scan of bucket totals -> bucket bases
__global__ __launch_bounds__(1024) void scan_buckets(const int* __restrict__ totals,
                                                     int* __restrict__ base_,
                                                     int* __restrict__ row_start) {
    __shared__ int s[1024];
    int t = threadIdx.x;
    int v = (t < NBKT) ? totals[t] : 0;
    s[t] = v;
    __syncthreads();
    for (int o = 1; o < 1024; o <<= 1) {
        int x = (t >= o) ? s[t - o] : 0;
        __syncthreads();
        s[t] += x;
        __syncthreads();
    }
    if (t < NBKT) base_[t] = s[t] - v;
    if (t == 0) { base_[NBKT] = N_EDGES; row_start[N_NODES] = N_EDGES; }
}

// coarse scatter into bucket-ordered tmp (LDS cursors, semi-coalesced writes)
__global__ __launch_bounds__(256) void coarse_scatter(
        const int* __restrict__ erow, const int* __restrict__ ecol,
        const float* __restrict__ eval,
        const int* __restrict__ hist, const int* __restrict__ base_,
        uint2* __restrict__ tmp) {
    __shared__ int lbase[NBKT];
    __shared__ int cnt[NBKT];
    for (int b = threadIdx.x; b < NBKT; b += 256) {
        lbase[b] = hist[blockIdx.x * NBKT + b] + base_[b];
        cnt[b] = 0;
    }
    __syncthreads();
    int cb = blockIdx.x * CHUNK;
    #pragma unroll
    for (int j = 0; j < CHUNK; j += 256) {
        int i = cb + j + threadIdx.x;
        if (i < N_EDGES) {
            int r = erow[i];
            int b = r >> 7;
            int pos = lbase[b] + atomicAdd(&cnt[b], 1);
            uint2 cv;
            cv.x = (unsigned)ecol[i] | ((unsigned)(r & 127) << 17);  // col < 2^17
            union { float f; unsigned u; } w; w.f = eval[i];
            cv.y = w.u;
            tmp[pos] = cv;
        }
    }
}

// fine counting sort within each 128-row bucket; writes CSR + row_start
__global__ __launch_bounds__(512) void fine_sort(const uint2* __restrict__ tmp,
                                                 const int* __restrict__ base_,
                                                 uint2* __restrict__ csr,
                                                 int* __restrict__ row_start) {
    __shared__ int cnt[RPB];
    __shared__ int excl[RPB];
    __shared__ int cur[RPB];
    int b = blockIdx.x;
    int t = threadIdx.x;
    int s0 = base_[b];
    int nb = base_[b + 1] - s0;
    if (t < RPB) cnt[t] = 0;
    __syncthreads();
    for (int j = t; j < nb; j += 512)
        atomicAdd(&cnt[(tmp[s0 + j].x >> 17) & 127], 1);
    __syncthreads();
    if (t < RPB) excl[t] = cnt[t];
    __syncthreads();
    for (int o = 1; o < RPB; o <<= 1) {
        int x = (t < RPB && t >= o) ? excl[t - o] : 0;
        __syncthreads();
        if (t < RPB) excl[t] += x;
        __syncthreads();
    }
    if (t < RPB) {
        int ex = excl[t] - cnt[t];
        excl[t] = ex;
        cur[t] = ex;
        int row = b * RPB + t;
        if (row < N_NODES) row_start[row] = s0 + ex;
    }
    __syncthreads();
    for (int j = t; j < nb; j += 512) {
        uint2 cv = tmp[s0 + j];
        unsigned rl = (cv.x >> 17) & 127;
        int dst = s0 + atomicAdd(&cur[rl], 1);
        csr[dst] = cv;
    }
}

// ---- SpMM: one wave per row, half-wave per edge, 4 in flight ------------
__global__ __launch_bounds__(256) void spmm_kernel(
        const ushort* __restrict__ xbf,           // [N][256] bf16
        const int* __restrict__ row_start,
        const uint2* __restrict__ csr_cv,         // col in low 17 bits of .x
        ushort* __restrict__ agg_bf) {            // [N][256] bf16
    int row  = (blockIdx.x * blockDim.x + threadIdx.x) >> 6;
    int lane = threadIdx.x & 63;
    int half = lane >> 5;
    int hl   = lane & 31;
    if (row >= N_NODES) return;
    int start = row_start[row];
    int end   = row_start[row + 1];
    float acc[8] = {0.f, 0.f, 0.f, 0.f, 0.f, 0.f, 0.f, 0.f};
    int e = start + half;
    for (; e + 6 < end; e += 8) {      // 4 edges in flight per half-wave
        uint2 c0 = csr_cv[e];
        uint2 c1 = csr_cv[e + 2];
        uint2 c2 = csr_cv[e + 4];
        uint2 c3 = csr_cv[e + 6];
        ushort8 v0 = *(const ushort8*)&xbf[(size_t)(c0.x & 0x1FFFF) * 256 + hl * 8];
        ushort8 v1 = *(const ushort8*)&xbf[(size_t)(c1.x & 0x1FFFF) * 256 + hl * 8];
        ushort8 v2 = *(const ushort8*)&xbf[(size_t)(c2.x & 0x1FFFF) * 256 + hl * 8];
        ushort8 v3 = *(const ushort8*)&xbf[(size_t)(c3.x & 0x1FFFF) * 256 + hl * 8];
        union { unsigned u; float f; } w0, w1, w2, w3;
        w0.u = c0.y; w1.u = c1.y; w2.u = c2.y; w3.u = c3.y;
        #pragma unroll
        for (int j = 0; j < 8; ++j) acc[j] += w0.f * bf2f(v0[j]);
        #pragma unroll
        for (int j = 0; j < 8; ++j) acc[j] += w1.f * bf2f(v1[j]);
        #pragma unroll
        for (int j = 0; j < 8; ++j) acc[j] += w2.f * bf2f(v2[j]);
        #pragma unroll
        for (int j = 0; j < 8; ++j) acc[j] += w3.f * bf2f(v3[j]);
    }
    for (; e < end; e += 2) {
        uint2 cv = csr_cv[e];
        ushort8 v = *(const ushort8*)&xbf[(size_t)(cv.x & 0x1FFFF) * 256 + hl * 8];
        union { unsigned u; float f; } w; w.u = cv.y;
        #pragma unroll
        for (int j = 0; j < 8; ++j) acc[j] += w.f * bf2f(v[j]);
    }
    #pragma unroll
    for (int j = 0; j < 8; ++j) acc[j] += __shfl_xor(acc[j], 32, 64);
    if (half == 0) {
        ushort8 o;
        #pragma unroll
        for (int j = 0; j < 8; ++j) o[j] = f2bf(acc[j]);
        *(ushort8*)&agg_bf[(size_t)row * 256 + hl * 8] = o;
    }
}

// ---- W fp32 -> bf16 ------------------------------------------------------
__global__ void wconv_kernel(const float* __restrict__ W, ushort* __restrict__ Wbf) {
    int i = blockIdx.x * 256 + threadIdx.x;
    Wbf[i] = f2bf(W[i]);
}

// ---- GEMM: 64 rows/block, 4x W reuse per wave ---------------------------
__global__ __launch_bounds__(256) void gemm_kernel(
        const ushort* __restrict__ Abf,   // [N][256] bf16
        const ushort* __restrict__ Wbf,   // [256][256] bf16, n-major
        float* __restrict__ out) {        // [N][256] fp32
    int w    = threadIdx.x >> 6;
    int lane = threadIdx.x & 63;
    int quad = lane >> 4;
    int l16  = lane & 15;
    int rt   = blockIdx.x * 64;           // 1563 blocks

    float4v acc[4][4];
    #pragma unroll
    for (int mt = 0; mt < 4; ++mt)
        #pragma unroll
        for (int nt = 0; nt < 4; ++nt) acc[mt][nt] = (float4v){0.f, 0.f, 0.f, 0.f};

    #pragma unroll
    for (int k0 = 0; k0 < 256; k0 += 32) {
        short8 a[4], bf[4];
        #pragma unroll
        for (int mt = 0; mt < 4; ++mt) {
            int row = rt + mt * 16 + l16;
            if (row >= N_NODES) row = N_NODES - 1;   // clamp (tail block)
            a[mt] = *(const short8*)&Abf[(size_t)row * 256 + k0 + quad * 8];
        }
        #pragma unroll
        for (int nt = 0; nt < 4; ++nt) {
            int n = w * 64 + nt * 16 + l16;
            bf[nt] = *(const short8*)&Wbf[n * 256 + k0 + quad * 8];
        }
        #pragma unroll
        for (int mt = 0; mt < 4; ++mt)
            #pragma unroll
            for (int nt = 0; nt < 4; ++nt)
                acc[mt][nt] = __builtin_amdgcn_mfma_f32_16x16x32_bf16(a[mt], bf[nt], acc[mt][nt], 0, 0, 0);
    }
    #pragma unroll
    for (int mt = 0; mt < 4; ++mt)
        #pragma unroll
        for (int nt = 0; nt < 4; ++nt) {
            int n = w * 64 + nt * 16 + l16;
            #pragma unroll
            for (int r = 0; r < 4; ++r) {
                int row = rt + mt * 16 + quad * 4 + r;   // C/D: col=lane&15, row=quad*4+reg
                if (row < N_NODES) out[(size_t)row * 256 + n] = acc[mt][nt][r];
            }
        }
}

// ---- launch --------------------------------------------------------------

extern "C" void kernel_launch(void* const* d_in, const int* in_sizes, int n_in,
                              void* d_out, int out_size, void* d_ws, size_t ws_size,
                              hipStream_t stream) {
    const float* x    = (const float*)d_in[0];
    const int*   erow = (const int*)d_in[1];
    const int*   ecol = (const int*)d_in[2];
    const float* eval = (const float*)d_in[3];
    const float* W    = (const float*)d_in[4];
    float* out = (float*)d_out;

    char* ws = (char*)d_ws;
    size_t off = 0;
    int* hist      = (int*)(ws + off);   off += ((size_t)NBLK_E * NBKT * 4 + 255) & ~255ull;
    int* totals    = (int*)(ws + off);   off += ((size_t)NBKT * 4 + 255) & ~255ull;
    int* base_     = (int*)(ws + off);   off += ((size_t)(NBKT + 1) * 4 + 255) & ~255ull;
    int* row_start = (int*)(ws + off);   off += ((size_t)(N_NODES + 1) * 4 + 255) & ~255ull;
    uint2* tmp_cv  = (uint2*)(ws + off); off += (size_t)N_EDGES * 8;
    uint2* csr_cv  = (uint2*)(ws + off); off += (size_t)N_EDGES * 8;
    ushort* Wbf    = (ushort*)(ws + off);  off += (size_t)D_FEAT * D_FEAT * 2;
    ushort* xbf    = (ushort*)(ws + off);  off += (size_t)N_NODES * D_FEAT * 2;
    ushort* agg_bf = (ushort*)(ws + off);  off += (size_t)N_NODES * D_FEAT * 2;

    xconv_kernel<<<(N_NODES * D_FEAT / 4) / 256, 256, 0, stream>>>((const float4*)x, (ushort4*)xbf);
    coarse_hist<<<NBLK_E, 256, 0, stream>>>(erow, hist);
    scan_blocks<<<NBKT, 512, 0, stream>>>(hist, totals);
    scan_buckets<<<1, 1024, 0, stream>>>(totals, base_, row_start);
    coarse_scatter<<<NBLK_E, 256, 0, stream>>>(erow, ecol, eval, hist, base_, tmp_cv);
    fine_sort<<<NBKT, 512, 0, stream>>>(tmp_cv, base_, csr_cv, row_start);
    wconv_kernel<<<(D_FEAT * D_FEAT) / 256, 256, 0, stream>>>(W, Wbf);
    spmm_kernel<<<N_NODES / 4, 256, 0, stream>>>(xbf, row_start, csr_cv, agg_bf);
    gemm_kernel<<<(N_NODES + 63) / 64, 256, 0, stream>>>(agg_bf, Wbf, out);
}